// Round 1
// baseline (152.122 us; speedup 1.0000x reference)
//
#include <hip/hip_runtime.h>
#include <hip/hip_bf16.h>
#include <stdint.h>

#define N_TOK 8192
#define DIM   512
#define HID   2048
#define OUTD  512
#define NEXP  8

typedef short  bf16x8 __attribute__((ext_vector_type(8)));
typedef float  f32x4  __attribute__((ext_vector_type(4)));
typedef unsigned short u16x8 __attribute__((ext_vector_type(8)));
typedef unsigned short u16x4 __attribute__((ext_vector_type(4)));

// ---- workspace layout (bytes) ----
#define WS_CNT    0        // 8 ints: per-expert token counters (atomic)
#define WS_NTILES 64       // 1 int
#define WS_BASE   128      // 8 ints: exclusive scan of counts
#define WS_DESC_E 256      // 96 ints: tile -> expert
#define WS_DESC_R 768      // 96 ints: tile -> row0 within expert list
#define WS_LIST   4096     // 8*8192 ints: per-expert token id lists
#define WS_XBF    266240   // 8192*512 bf16 (x converted)
#define WS_W1T    8654848  // 8*2048*512 bf16 (W1 transposed: [e][h][d])
#define WS_W2T    25432064 // 8*512*2048 bf16 (W2 transposed: [e][o][h])
#define WS_H      42209280 // 8192*2048 bf16 (hidden, expert-compacted rows)

__device__ __forceinline__ unsigned short f2bf(float f) {
    uint32_t u = __builtin_bit_cast(uint32_t, f);
    u = (u + 0x7fffu + ((u >> 16) & 1u)) >> 16;   // RNE
    return (unsigned short)u;
}

__global__ void init_kernel(int* cnt) {
    if (threadIdx.x < NEXP) cnt[threadIdx.x] = 0;
}

// ---- fp32 router: logits -> softmax -> probs out, argmax -> expert lists ----
__global__ __launch_bounds__(256) void router_kernel(
    const float* __restrict__ x, const float* __restrict__ wr,
    const float* __restrict__ br, float* __restrict__ probs,
    int* __restrict__ cnt, int* __restrict__ list)
{
    __shared__ int lcnt[NEXP];
    __shared__ int lbase[NEXP];
    const int tid = threadIdx.x;
    if (tid < NEXP) lcnt[tid] = 0;
    __syncthreads();

    const int n = blockIdx.x * 256 + tid;
    float acc[NEXP];
    #pragma unroll
    for (int e = 0; e < NEXP; e++) acc[e] = br[e];

    const f32x4* xr = (const f32x4*)(x + (size_t)n * DIM);
    for (int i = 0; i < DIM / 4; i++) {
        f32x4 v = xr[i];
        #pragma unroll
        for (int d = 0; d < 4; d++) {
            const float xv = v[d];
            #pragma unroll
            for (int e = 0; e < NEXP; e++)
                acc[e] += xv * wr[(i * 4 + d) * NEXP + e];  // uniform addr -> scalar load
        }
    }
    // softmax + argmax (first-max wins, matches numpy)
    float mx = acc[0]; int am = 0;
    #pragma unroll
    for (int e = 1; e < NEXP; e++) if (acc[e] > mx) { mx = acc[e]; am = e; }
    float p[NEXP]; float s = 0.f;
    #pragma unroll
    for (int e = 0; e < NEXP; e++) { p[e] = expf(acc[e] - mx); s += p[e]; }
    const float inv = 1.f / s;
    f32x4 p0, p1;
    #pragma unroll
    for (int e = 0; e < 4; e++) { p0[e] = p[e] * inv; p1[e] = p[e + 4] * inv; }
    *(f32x4*)&probs[(size_t)n * NEXP]     = p0;
    *(f32x4*)&probs[(size_t)n * NEXP + 4] = p1;

    const int slot = atomicAdd(&lcnt[am], 1);
    __syncthreads();
    if (tid < NEXP) lbase[tid] = atomicAdd(&cnt[tid], lcnt[tid]);
    __syncthreads();
    list[am * N_TOK + lbase[am] + slot] = n;
}

__global__ void convert_x_kernel(const float* __restrict__ x, unsigned short* __restrict__ xbf) {
    const size_t i = (size_t)blockIdx.x * 256 + threadIdx.x;   // 524288 threads, 8 elems each
    f32x4 a = *(const f32x4*)&x[i * 8];
    f32x4 b = *(const f32x4*)&x[i * 8 + 4];
    u16x8 o;
    #pragma unroll
    for (int j = 0; j < 4; j++) { o[j] = f2bf(a[j]); o[4 + j] = f2bf(b[j]); }
    *(u16x8*)&xbf[i * 8] = o;
}

// in: [E][R][C] f32  ->  out: [E][C][R] bf16
__global__ __launch_bounds__(256) void transpose_bf16_kernel(
    const float* __restrict__ in, unsigned short* __restrict__ out, int R, int C)
{
    __shared__ float t[32][33];
    const int e = blockIdx.z;
    const float* pin = in + (size_t)e * R * C;
    unsigned short* pout = out + (size_t)e * R * C;
    const int r0 = blockIdx.x * 32, c0 = blockIdx.y * 32;
    const int lr = threadIdx.x >> 3, lc4 = (threadIdx.x & 7) * 4;
    f32x4 v = *(const f32x4*)&pin[(size_t)(r0 + lr) * C + c0 + lc4];
    #pragma unroll
    for (int i = 0; i < 4; i++) t[lr][lc4 + i] = v[i];
    __syncthreads();
    u16x4 o;
    #pragma unroll
    for (int i = 0; i < 4; i++) o[i] = f2bf(t[lc4 + i][lr]);
    *(u16x4*)&pout[(size_t)(c0 + lr) * R + r0 + lc4] = o;
}

__global__ void scheduler_kernel(const int* __restrict__ cnt, int* __restrict__ base,
                                 int* __restrict__ desc_e, int* __restrict__ desc_r,
                                 int* __restrict__ ntiles, float* __restrict__ counts_out)
{
    if (threadIdx.x == 0) {
        int b = 0, t = 0;
        for (int e = 0; e < NEXP; e++) {
            base[e] = b;
            const int m = cnt[e]; b += m;
            for (int r = 0; r < m; r += 128) { desc_e[t] = e; desc_r[t] = r; t++; }
        }
        *ntiles = t;
    }
    if (threadIdx.x < NEXP) counts_out[threadIdx.x] = (float)cnt[threadIdx.x];
}

// ---- GEMM1: h[slot, :] = relu(x[tok] @ W1[e] + b1[e]) ; tile 128x128, BK=64 ----
__global__ __launch_bounds__(256) void gemm1_kernel(
    const unsigned short* __restrict__ xbf, const unsigned short* __restrict__ w1t,
    const float* __restrict__ b1, const int* __restrict__ list,
    const int* __restrict__ cnt, const int* __restrict__ base,
    const int* __restrict__ desc_e, const int* __restrict__ desc_r,
    const int* __restrict__ ntiles, unsigned short* __restrict__ h)
{
    if ((int)blockIdx.x >= *ntiles) return;
    const int e    = desc_e[blockIdx.x];
    const int row0 = desc_r[blockIdx.x];
    const int m_e  = cnt[e];
    const int n0   = blockIdx.y * 128;

    __shared__ unsigned short ldsA[128 * 72];
    __shared__ unsigned short ldsB[128 * 72];
    __shared__ int ldsTok[128];
    const int tid = threadIdx.x;
    if (tid < 128) {
        int r = row0 + tid; if (r >= m_e) r = m_e - 1;
        ldsTok[tid] = list[e * N_TOK + r];
    }
    __syncthreads();

    const int seg = tid & 7;
    const unsigned short* aptr[4]; const unsigned short* bptr[4]; int loff[4];
    #pragma unroll
    for (int i = 0; i < 4; i++) {
        const int r = (i * 256 + tid) >> 3;
        aptr[i] = xbf + (size_t)ldsTok[r] * DIM + seg * 8;
        bptr[i] = w1t + ((size_t)e * HID + n0 + r) * DIM + seg * 8;
        loff[i] = r * 72 + seg * 8;
    }

    f32x4 acc[4][4] = {};
    const int lane = tid & 63, wid = tid >> 6;
    const int wm = (wid >> 1) * 64, wn = (wid & 1) * 64;
    const int lrow = lane & 15, lk = (lane >> 4) * 8;

    for (int k0 = 0; k0 < DIM; k0 += 64) {
        __syncthreads();
        #pragma unroll
        for (int i = 0; i < 4; i++) {
            *(bf16x8*)&ldsA[loff[i]] = *(const bf16x8*)(aptr[i] + k0);
            *(bf16x8*)&ldsB[loff[i]] = *(const bf16x8*)(bptr[i] + k0);
        }
        __syncthreads();
        #pragma unroll
        for (int kk = 0; kk < 64; kk += 32) {
            bf16x8 av[4], bv[4];
            #pragma unroll
            for (int f = 0; f < 4; f++) {
                av[f] = *(const bf16x8*)&ldsA[(wm + f * 16 + lrow) * 72 + kk + lk];
                bv[f] = *(const bf16x8*)&ldsB[(wn + f * 16 + lrow) * 72 + kk + lk];
            }
            #pragma unroll
            for (int mf = 0; mf < 4; mf++)
                #pragma unroll
                for (int nf = 0; nf < 4; nf++)
                    acc[mf][nf] = __builtin_amdgcn_mfma_f32_16x16x32_bf16(av[mf], bv[nf], acc[mf][nf], 0, 0, 0);
        }
    }

    const int hbase = base[e] + row0;
    float bias[4];
    #pragma unroll
    for (int nf = 0; nf < 4; nf++) bias[nf] = b1[e * HID + n0 + wn + nf * 16 + lrow];
    #pragma unroll
    for (int mf = 0; mf < 4; mf++) {
        #pragma unroll
        for (int j = 0; j < 4; j++) {
            const int m = wm + mf * 16 + (lane >> 4) * 4 + j;
            if (row0 + m < m_e) {
                const size_t ro = (size_t)(hbase + m) * HID + n0 + wn;
                #pragma unroll
                for (int nf = 0; nf < 4; nf++) {
                    float v = acc[mf][nf][j] + bias[nf];
                    h[ro + nf * 16 + lrow] = f2bf(v > 0.f ? v : 0.f);
                }
            }
        }
    }
}

// ---- GEMM2: out[tok, :] = h[slot] @ W2[e] + b2[e] ; tile 128x64, BK=64, K=2048 ----
__global__ __launch_bounds__(256) void gemm2_kernel(
    const unsigned short* __restrict__ h, const unsigned short* __restrict__ w2t,
    const float* __restrict__ b2, const int* __restrict__ list,
    const int* __restrict__ cnt, const int* __restrict__ base,
    const int* __restrict__ desc_e, const int* __restrict__ desc_r,
    const int* __restrict__ ntiles, float* __restrict__ out)
{
    if ((int)blockIdx.x >= *ntiles) return;
    const int e    = desc_e[blockIdx.x];
    const int row0 = desc_r[blockIdx.x];
    const int m_e  = cnt[e];
    const int n0   = blockIdx.y * 64;
    const int be   = base[e];

    __shared__ unsigned short ldsA[128 * 72];
    __shared__ unsigned short ldsB[64 * 72];
    __shared__ int ldsTok[128];
    const int tid = threadIdx.x;
    if (tid < 128) {
        int r = row0 + tid; if (r >= m_e) r = m_e - 1;
        ldsTok[tid] = list[e * N_TOK + r];
    }

    const int seg = tid & 7;
    const unsigned short* aptr[4]; const unsigned short* bptr[2]; int loffA[4], loffB[2];
    #pragma unroll
    for (int i = 0; i < 4; i++) {
        const int r = (i * 256 + tid) >> 3;
        int slot = row0 + r; if (slot >= m_e) slot = m_e - 1;
        aptr[i]  = h + (size_t)(be + slot) * HID + seg * 8;
        loffA[i] = r * 72 + seg * 8;
    }
    #pragma unroll
    for (int i = 0; i < 2; i++) {
        const int r = (i * 256 + tid) >> 3;   // 0..63
        bptr[i]  = w2t + ((size_t)e * OUTD + n0 + r) * HID + seg * 8;
        loffB[i] = r * 72 + seg * 8;
    }

    f32x4 acc[4][2] = {};
    const int lane = tid & 63, wid = tid >> 6;
    const int wm = (wid >> 1) * 64, wn = (wid & 1) * 32;
    const int lrow = lane & 15, lk = (lane >> 4) * 8;

    for (int k0 = 0; k0 < HID; k0 += 64) {
        __syncthreads();
        #pragma unroll
        for (int i = 0; i < 4; i++)
            *(bf16x8*)&ldsA[loffA[i]] = *(const bf16x8*)(aptr[i] + k0);
        #pragma unroll
        for (int i = 0; i < 2; i++)
            *(bf16x8*)&ldsB[loffB[i]] = *(const bf16x8*)(bptr[i] + k0);
        __syncthreads();
        #pragma unroll
        for (int kk = 0; kk < 64; kk += 32) {
            bf16x8 av[4], bv[2];
            #pragma unroll
            for (int f = 0; f < 4; f++)
                av[f] = *(const bf16x8*)&ldsA[(wm + f * 16 + lrow) * 72 + kk + lk];
            #pragma unroll
            for (int f = 0; f < 2; f++)
                bv[f] = *(const bf16x8*)&ldsB[(wn + f * 16 + lrow) * 72 + kk + lk];
            #pragma unroll
            for (int mf = 0; mf < 4; mf++)
                #pragma unroll
                for (int nf = 0; nf < 2; nf++)
                    acc[mf][nf] = __builtin_amdgcn_mfma_f32_16x16x32_bf16(av[mf], bv[nf], acc[mf][nf], 0, 0, 0);
        }
    }

    float bias[2];
    #pragma unroll
    for (int nf = 0; nf < 2; nf++) bias[nf] = b2[e * OUTD + n0 + wn + nf * 16 + lrow];
    #pragma unroll
    for (int mf = 0; mf < 4; mf++) {
        #pragma unroll
        for (int j = 0; j < 4; j++) {
            const int m = wm + mf * 16 + (lane >> 4) * 4 + j;
            if (row0 + m < m_e) {
                const size_t ro = (size_t)ldsTok[m] * OUTD + n0 + wn;
                #pragma unroll
                for (int nf = 0; nf < 2; nf++)
                    out[ro + nf * 16 + lrow] = acc[mf][nf][j] + bias[nf];
            }
        }
    }
}

extern "C" void kernel_launch(void* const* d_in, const int* in_sizes, int n_in,
                              void* d_out, int out_size, void* d_ws, size_t ws_size,
                              hipStream_t stream) {
    (void)in_sizes; (void)n_in; (void)out_size; (void)ws_size;
    const float* x  = (const float*)d_in[0];
    const float* wr = (const float*)d_in[1];
    const float* br = (const float*)d_in[2];
    const float* w1 = (const float*)d_in[3];
    const float* b1 = (const float*)d_in[4];
    const float* w2 = (const float*)d_in[5];
    const float* b2 = (const float*)d_in[6];

    float* out    = (float*)d_out;
    float* probs  = out + (size_t)N_TOK * OUTD;
    float* counts = probs + (size_t)N_TOK * NEXP;

    char* ws = (char*)d_ws;
    int* cnt     = (int*)(ws + WS_CNT);
    int* ntiles  = (int*)(ws + WS_NTILES);
    int* basep   = (int*)(ws + WS_BASE);
    int* desc_e  = (int*)(ws + WS_DESC_E);
    int* desc_r  = (int*)(ws + WS_DESC_R);
    int* list    = (int*)(ws + WS_LIST);
    unsigned short* xbf = (unsigned short*)(ws + WS_XBF);
    unsigned short* w1t = (unsigned short*)(ws + WS_W1T);
    unsigned short* w2t = (unsigned short*)(ws + WS_W2T);
    unsigned short* hbf = (unsigned short*)(ws + WS_H);

    init_kernel<<<1, 64, 0, stream>>>(cnt);
    router_kernel<<<32, 256, 0, stream>>>(x, wr, br, probs, cnt, list);
    convert_x_kernel<<<2048, 256, 0, stream>>>(x, xbf);
    transpose_bf16_kernel<<<dim3(16, 64, NEXP), 256, 0, stream>>>(w1, w1t, DIM, HID);
    transpose_bf16_kernel<<<dim3(64, 16, NEXP), 256, 0, stream>>>(w2, w2t, HID, OUTD);
    scheduler_kernel<<<1, 64, 0, stream>>>(cnt, basep, desc_e, desc_r, ntiles, counts);
    gemm1_kernel<<<dim3(80, 16), 256, 0, stream>>>(xbf, w1t, b1, list, cnt, basep, desc_e, desc_r, ntiles, hbf);
    gemm2_kernel<<<dim3(80, 8), 256, 0, stream>>>(hbf, w2t, b2, list, cnt, basep, desc_e, desc_r, ntiles, out);
}

// Round 2
// 130.822 us; speedup vs baseline: 1.1628x; 1.1628x over previous
//
#include <hip/hip_runtime.h>
#include <hip/hip_bf16.h>
#include <stdint.h>

#define N_TOK 8192
#define DIM   512
#define HID   2048
#define OUTD  512
#define NEXP  8

typedef short  bf16x8 __attribute__((ext_vector_type(8)));
typedef float  f32x4  __attribute__((ext_vector_type(4)));
typedef unsigned short u16x8 __attribute__((ext_vector_type(8)));
typedef unsigned short u16x4 __attribute__((ext_vector_type(4)));

// ---- workspace layout (bytes) ----
#define WS_CNT    0        // 8 ints: per-expert token counters (atomic)
#define WS_NTILES 64       // 1 int
#define WS_BASE   128      // 8 ints: exclusive scan of counts
#define WS_DESC_E 256      // 96 ints: tile -> expert
#define WS_DESC_R 768      // 96 ints: tile -> row0 within expert list
#define WS_LIST   4096     // 8*8192 ints: per-expert token id lists
#define WS_XBF    266240   // 8192*512 bf16 (x converted)
#define WS_W1T    8654848  // 8*2048*512 bf16 (W1 transposed: [e][h][d])
#define WS_W2T    25432064 // 8*512*2048 bf16 (W2 transposed: [e][o][h])
#define WS_H      42209280 // 8192*2048 bf16 (hidden, expert-compacted rows)

__device__ __forceinline__ unsigned short f2bf(float f) {
    uint32_t u = __builtin_bit_cast(uint32_t, f);
    u = (u + 0x7fffu + ((u >> 16) & 1u)) >> 16;   // RNE
    return (unsigned short)u;
}

// async global->LDS, 16B per lane; LDS dest = wave-uniform base + lane*16
__device__ __forceinline__ void gload16(const unsigned short* g, unsigned short* l) {
    __builtin_amdgcn_global_load_lds(
        (const __attribute__((address_space(1))) unsigned int*)g,
        (__attribute__((address_space(3))) unsigned int*)l, 16, 0, 0);
}

__global__ void init_kernel(int* cnt) {
    if (threadIdx.x < NEXP) cnt[threadIdx.x] = 0;
}

// ---- fp32 router: logits -> softmax -> probs out, argmax -> expert lists ----
__global__ __launch_bounds__(256) void router_kernel(
    const float* __restrict__ x, const float* __restrict__ wr,
    const float* __restrict__ br, float* __restrict__ probs,
    int* __restrict__ cnt, int* __restrict__ list)
{
    __shared__ int lcnt[NEXP];
    __shared__ int lbase[NEXP];
    const int tid = threadIdx.x;
    if (tid < NEXP) lcnt[tid] = 0;
    __syncthreads();

    const int n = blockIdx.x * 256 + tid;
    float acc[NEXP];
    #pragma unroll
    for (int e = 0; e < NEXP; e++) acc[e] = br[e];

    const f32x4* xr = (const f32x4*)(x + (size_t)n * DIM);
    for (int i = 0; i < DIM / 4; i++) {
        f32x4 v = xr[i];
        #pragma unroll
        for (int d = 0; d < 4; d++) {
            const float xv = v[d];
            #pragma unroll
            for (int e = 0; e < NEXP; e++)
                acc[e] += xv * wr[(i * 4 + d) * NEXP + e];  // uniform addr -> scalar load
        }
    }
    // softmax + argmax (first-max wins, matches numpy)
    float mx = acc[0]; int am = 0;
    #pragma unroll
    for (int e = 1; e < NEXP; e++) if (acc[e] > mx) { mx = acc[e]; am = e; }
    float p[NEXP]; float s = 0.f;
    #pragma unroll
    for (int e = 0; e < NEXP; e++) { p[e] = expf(acc[e] - mx); s += p[e]; }
    const float inv = 1.f / s;
    f32x4 p0, p1;
    #pragma unroll
    for (int e = 0; e < 4; e++) { p0[e] = p[e] * inv; p1[e] = p[e + 4] * inv; }
    *(f32x4*)&probs[(size_t)n * NEXP]     = p0;
    *(f32x4*)&probs[(size_t)n * NEXP + 4] = p1;

    const int slot = atomicAdd(&lcnt[am], 1);
    __syncthreads();
    if (tid < NEXP) lbase[tid] = atomicAdd(&cnt[tid], lcnt[tid]);
    __syncthreads();
    list[am * N_TOK + lbase[am] + slot] = n;
}

__global__ void convert_x_kernel(const float* __restrict__ x, unsigned short* __restrict__ xbf) {
    const size_t i = (size_t)blockIdx.x * 256 + threadIdx.x;   // 524288 threads, 8 elems each
    f32x4 a = *(const f32x4*)&x[i * 8];
    f32x4 b = *(const f32x4*)&x[i * 8 + 4];
    u16x8 o;
    #pragma unroll
    for (int j = 0; j < 4; j++) { o[j] = f2bf(a[j]); o[4 + j] = f2bf(b[j]); }
    *(u16x8*)&xbf[i * 8] = o;
}

// in: [E][R][C] f32  ->  out: [E][C][R] bf16
__global__ __launch_bounds__(256) void transpose_bf16_kernel(
    const float* __restrict__ in, unsigned short* __restrict__ out, int R, int C)
{
    __shared__ float t[32][33];
    const int e = blockIdx.z;
    const float* pin = in + (size_t)e * R * C;
    unsigned short* pout = out + (size_t)e * R * C;
    const int r0 = blockIdx.x * 32, c0 = blockIdx.y * 32;
    const int lr = threadIdx.x >> 3, lc4 = (threadIdx.x & 7) * 4;
    f32x4 v = *(const f32x4*)&pin[(size_t)(r0 + lr) * C + c0 + lc4];
    #pragma unroll
    for (int i = 0; i < 4; i++) t[lr][lc4 + i] = v[i];
    __syncthreads();
    u16x4 o;
    #pragma unroll
    for (int i = 0; i < 4; i++) o[i] = f2bf(t[lc4 + i][lr]);
    *(u16x4*)&pout[(size_t)(c0 + lr) * R + r0 + lc4] = o;
}

__global__ void scheduler_kernel(const int* __restrict__ cnt, int* __restrict__ base,
                                 int* __restrict__ desc_e, int* __restrict__ desc_r,
                                 int* __restrict__ ntiles, float* __restrict__ counts_out)
{
    if (threadIdx.x == 0) {
        int b = 0, t = 0;
        for (int e = 0; e < NEXP; e++) {
            base[e] = b;
            const int m = cnt[e]; b += m;
            for (int r = 0; r < m; r += 128) { desc_e[t] = e; desc_r[t] = r; t++; }
        }
        *ntiles = t;
    }
    if (threadIdx.x < NEXP) counts_out[threadIdx.x] = (float)cnt[threadIdx.x];
}

// bijective per-XCD chunk swizzle: phys bid -> virtual id in [0,nwg)
__device__ __forceinline__ int xcd_swizzle(int bid, int nwg, bool& valid) {
    const int xcd = bid & 7, cidx = bid >> 3;
    const int q = nwg >> 3, r = nwg & 7;
    const int csz = q + (xcd < r ? 1 : 0);
    valid = (cidx < csz);
    return (xcd < r ? xcd * (q + 1) : r * (q + 1) + (xcd - r) * q) + cidx;
}

// ---- GEMM1: h[slot, :] = relu(x[tok] @ W1[e] + b1[e]) ; tile 128x128, BK=64 ----
// global_load_lds(16B) staging, linear LDS [row][64] with XOR col-granule swizzle.
__global__ __launch_bounds__(256) void gemm1_kernel(
    const unsigned short* __restrict__ xbf, const unsigned short* __restrict__ w1t,
    const float* __restrict__ b1, const int* __restrict__ list,
    const int* __restrict__ cnt, const int* __restrict__ base,
    const int* __restrict__ desc_e, const int* __restrict__ desc_r,
    const int* __restrict__ ntiles, unsigned short* __restrict__ h)
{
    const int nwg = *ntiles * 16;
    bool valid; const int v = xcd_swizzle(blockIdx.x, nwg, valid);
    if (!valid) return;
    const int tile = v >> 4, ntile = v & 15;      // v = tile*16 + ntile: A+B L2-chunked per XCD
    const int e    = desc_e[tile];
    const int row0 = desc_r[tile];
    const int m_e  = cnt[e];
    const int n0   = ntile * 128;

    __shared__ unsigned short ldsA[128 * 64] __attribute__((aligned(16)));
    __shared__ unsigned short ldsB[128 * 64] __attribute__((aligned(16)));
    __shared__ int ldsTok[128];
    const int tid = threadIdx.x;
    if (tid < 128) {
        int r = row0 + tid; if (r >= m_e) r = m_e - 1;
        ldsTok[tid] = list[e * N_TOK + r];
    }
    __syncthreads();

    // staging sources: round i covers rows [i*32, i*32+32); lane's col granule pre-swizzled
    const int gslot = tid & 7;
    const unsigned short* aSrc[4]; const unsigned short* bSrc[4];
    #pragma unroll
    for (int i = 0; i < 4; i++) {
        const int row = (i * 256 + tid) >> 3;
        const int col = ((gslot ^ (row & 7)) << 3);
        aSrc[i] = xbf + (size_t)ldsTok[row] * DIM + col;
        bSrc[i] = w1t + ((size_t)e * HID + n0 + row) * DIM + col;
    }

    f32x4 acc[4][4] = {};
    const int lane = tid & 63, wid = tid >> 6;
    const int wm = (wid >> 1) * 64, wn = (wid & 1) * 64;
    const int lrow = lane & 15, gk = lane >> 4;

    int offA[4][2], offB[4][2];
    #pragma unroll
    for (int f = 0; f < 4; f++) {
        const int ra = wm + f * 16 + lrow, rb = wn + f * 16 + lrow;
        #pragma unroll
        for (int kk = 0; kk < 2; kk++) {
            offA[f][kk] = ra * 64 + (((kk * 4 + gk) ^ (ra & 7)) << 3);
            offB[f][kk] = rb * 64 + (((kk * 4 + gk) ^ (rb & 7)) << 3);
        }
    }

    for (int k0 = 0; k0 < DIM; k0 += 64) {
        __syncthreads();
        #pragma unroll
        for (int i = 0; i < 4; i++) {
            const int lb = ((i << 8) + (tid & 192)) * 8;   // wave-uniform LDS base (elems)
            gload16(aSrc[i] + k0, ldsA + lb);
            gload16(bSrc[i] + k0, ldsB + lb);
        }
        __syncthreads();   // drains vmcnt(0) before barrier
        #pragma unroll
        for (int kk = 0; kk < 2; kk++) {
            bf16x8 av[4], bv[4];
            #pragma unroll
            for (int f = 0; f < 4; f++) {
                av[f] = *(const bf16x8*)&ldsA[offA[f][kk]];
                bv[f] = *(const bf16x8*)&ldsB[offB[f][kk]];
            }
            #pragma unroll
            for (int mf = 0; mf < 4; mf++)
                #pragma unroll
                for (int nf = 0; nf < 4; nf++)
                    acc[mf][nf] = __builtin_amdgcn_mfma_f32_16x16x32_bf16(av[mf], bv[nf], acc[mf][nf], 0, 0, 0);
        }
    }

    const int hbase = base[e] + row0;
    float bias[4];
    #pragma unroll
    for (int nf = 0; nf < 4; nf++) bias[nf] = b1[e * HID + n0 + wn + nf * 16 + lrow];
    #pragma unroll
    for (int mf = 0; mf < 4; mf++) {
        #pragma unroll
        for (int j = 0; j < 4; j++) {
            const int m = wm + mf * 16 + (lane >> 4) * 4 + j;
            if (row0 + m < m_e) {
                const size_t ro = (size_t)(hbase + m) * HID + n0 + wn;
                #pragma unroll
                for (int nf = 0; nf < 4; nf++) {
                    float vv = acc[mf][nf][j] + bias[nf];
                    h[ro + nf * 16 + lrow] = f2bf(vv > 0.f ? vv : 0.f);
                }
            }
        }
    }
}

// ---- GEMM2: out[tok, :] = h[slot] @ W2[e] + b2[e] ; tile 128x64, BK=64, K=2048 ----
__global__ __launch_bounds__(256) void gemm2_kernel(
    const unsigned short* __restrict__ h, const unsigned short* __restrict__ w2t,
    const float* __restrict__ b2, const int* __restrict__ list,
    const int* __restrict__ cnt, const int* __restrict__ base,
    const int* __restrict__ desc_e, const int* __restrict__ desc_r,
    const int* __restrict__ ntiles, float* __restrict__ out)
{
    const int nwg = *ntiles * 8;
    bool valid; const int v = xcd_swizzle(blockIdx.x, nwg, valid);
    if (!valid) return;
    const int tile = v >> 3, ntile = v & 7;
    const int e    = desc_e[tile];
    const int row0 = desc_r[tile];
    const int m_e  = cnt[e];
    const int n0   = ntile * 64;
    const int be   = base[e];

    __shared__ unsigned short ldsA[128 * 64] __attribute__((aligned(16)));
    __shared__ unsigned short ldsB[64 * 64]  __attribute__((aligned(16)));
    __shared__ int ldsTok[128];
    const int tid = threadIdx.x;
    if (tid < 128) {
        int r = row0 + tid; if (r >= m_e) r = m_e - 1;
        ldsTok[tid] = list[e * N_TOK + r];
    }

    const int gslot = tid & 7;
    const unsigned short* aSrc[4]; const unsigned short* bSrc[2];
    #pragma unroll
    for (int i = 0; i < 4; i++) {
        const int row = (i * 256 + tid) >> 3;
        int slot = row0 + row; if (slot >= m_e) slot = m_e - 1;
        aSrc[i] = h + (size_t)(be + slot) * HID + ((gslot ^ (row & 7)) << 3);
    }
    #pragma unroll
    for (int i = 0; i < 2; i++) {
        const int row = (i * 256 + tid) >> 3;   // 0..63
        bSrc[i] = w2t + ((size_t)e * OUTD + n0 + row) * HID + ((gslot ^ (row & 7)) << 3);
    }

    f32x4 acc[4][2] = {};
    const int lane = tid & 63, wid = tid >> 6;
    const int wm = (wid >> 1) * 64, wn = (wid & 1) * 32;
    const int lrow = lane & 15, gk = lane >> 4;

    int offA[4][2], offB[2][2];
    #pragma unroll
    for (int f = 0; f < 4; f++) {
        const int ra = wm + f * 16 + lrow;
        #pragma unroll
        for (int kk = 0; kk < 2; kk++)
            offA[f][kk] = ra * 64 + (((kk * 4 + gk) ^ (ra & 7)) << 3);
    }
    #pragma unroll
    for (int f = 0; f < 2; f++) {
        const int rb = wn + f * 16 + lrow;
        #pragma unroll
        for (int kk = 0; kk < 2; kk++)
            offB[f][kk] = rb * 64 + (((kk * 4 + gk) ^ (rb & 7)) << 3);
    }

    for (int k0 = 0; k0 < HID; k0 += 64) {
        __syncthreads();
        #pragma unroll
        for (int i = 0; i < 4; i++) {
            const int lb = ((i << 8) + (tid & 192)) * 8;
            gload16(aSrc[i] + k0, ldsA + lb);
        }
        #pragma unroll
        for (int i = 0; i < 2; i++) {
            const int lb = ((i << 8) + (tid & 192)) * 8;
            gload16(bSrc[i] + k0, ldsB + lb);
        }
        __syncthreads();
        #pragma unroll
        for (int kk = 0; kk < 2; kk++) {
            bf16x8 av[4], bv[2];
            #pragma unroll
            for (int f = 0; f < 4; f++)
                av[f] = *(const bf16x8*)&ldsA[offA[f][kk]];
            #pragma unroll
            for (int f = 0; f < 2; f++)
                bv[f] = *(const bf16x8*)&ldsB[offB[f][kk]];
            #pragma unroll
            for (int mf = 0; mf < 4; mf++)
                #pragma unroll
                for (int nf = 0; nf < 2; nf++)
                    acc[mf][nf] = __builtin_amdgcn_mfma_f32_16x16x32_bf16(av[mf], bv[nf], acc[mf][nf], 0, 0, 0);
        }
    }

    float bias[2];
    #pragma unroll
    for (int nf = 0; nf < 2; nf++) bias[nf] = b2[e * OUTD + n0 + wn + nf * 16 + lrow];
    #pragma unroll
    for (int mf = 0; mf < 4; mf++) {
        #pragma unroll
        for (int j = 0; j < 4; j++) {
            const int m = wm + mf * 16 + (lane >> 4) * 4 + j;
            if (row0 + m < m_e) {
                const size_t ro = (size_t)ldsTok[m] * OUTD + n0 + wn;
                #pragma unroll
                for (int nf = 0; nf < 2; nf++)
                    out[ro + nf * 16 + lrow] = acc[mf][nf][j] + bias[nf];
            }
        }
    }
}

extern "C" void kernel_launch(void* const* d_in, const int* in_sizes, int n_in,
                              void* d_out, int out_size, void* d_ws, size_t ws_size,
                              hipStream_t stream) {
    (void)in_sizes; (void)n_in; (void)out_size; (void)ws_size;
    const float* x  = (const float*)d_in[0];
    const float* wr = (const float*)d_in[1];
    const float* br = (const float*)d_in[2];
    const float* w1 = (const float*)d_in[3];
    const float* b1 = (const float*)d_in[4];
    const float* w2 = (const float*)d_in[5];
    const float* b2 = (const float*)d_in[6];

    float* out    = (float*)d_out;
    float* probs  = out + (size_t)N_TOK * OUTD;
    float* counts = probs + (size_t)N_TOK * NEXP;

    char* ws = (char*)d_ws;
    int* cnt     = (int*)(ws + WS_CNT);
    int* ntiles  = (int*)(ws + WS_NTILES);
    int* basep   = (int*)(ws + WS_BASE);
    int* desc_e  = (int*)(ws + WS_DESC_E);
    int* desc_r  = (int*)(ws + WS_DESC_R);
    int* list    = (int*)(ws + WS_LIST);
    unsigned short* xbf = (unsigned short*)(ws + WS_XBF);
    unsigned short* w1t = (unsigned short*)(ws + WS_W1T);
    unsigned short* w2t = (unsigned short*)(ws + WS_W2T);
    unsigned short* hbf = (unsigned short*)(ws + WS_H);

    init_kernel<<<1, 64, 0, stream>>>(cnt);
    router_kernel<<<32, 256, 0, stream>>>(x, wr, br, probs, cnt, list);
    convert_x_kernel<<<2048, 256, 0, stream>>>(x, xbf);
    transpose_bf16_kernel<<<dim3(16, 64, NEXP), 256, 0, stream>>>(w1, w1t, DIM, HID);
    transpose_bf16_kernel<<<dim3(64, 16, NEXP), 256, 0, stream>>>(w2, w2t, HID, OUTD);
    scheduler_kernel<<<1, 64, 0, stream>>>(cnt, basep, desc_e, desc_r, ntiles, counts);
    gemm1_kernel<<<1280, 256, 0, stream>>>(xbf, w1t, b1, list, cnt, basep, desc_e, desc_r, ntiles, hbf);
    gemm2_kernel<<<640, 256, 0, stream>>>(hbf, w2t, b2, list, cnt, basep, desc_e, desc_r, ntiles, out);
}

// Round 3
// 126.320 us; speedup vs baseline: 1.2043x; 1.0356x over previous
//
#include <hip/hip_runtime.h>
#include <hip/hip_bf16.h>
#include <stdint.h>

#define N_TOK 8192
#define DIM   512
#define HID   2048
#define OUTD  512
#define NEXP  8

typedef short  bf16x8 __attribute__((ext_vector_type(8)));
typedef float  f32x4  __attribute__((ext_vector_type(4)));
typedef unsigned short u16x8 __attribute__((ext_vector_type(8)));
typedef unsigned short u16x4 __attribute__((ext_vector_type(4)));

// ---- workspace layout (bytes) ----
#define WS_CNT    0        // 8 ints: per-expert token counters (atomic)
#define WS_LIST   4096     // 8*8192 ints: per-expert token id lists
#define WS_XBF    266240   // 8192*512 bf16 (x converted)
#define WS_W1T    8654848  // 8*2048*512 bf16 (W1 transposed: [e][h][d])
#define WS_W2T    25432064 // 8*512*2048 bf16 (W2 transposed: [e][o][h])
#define WS_H      42209280 // 8192*2048 bf16 (hidden, expert-compacted rows)

__device__ __forceinline__ unsigned short f2bf(float f) {
    uint32_t u = __builtin_bit_cast(uint32_t, f);
    u = (u + 0x7fffu + ((u >> 16) & 1u)) >> 16;   // RNE
    return (unsigned short)u;
}

// async global->LDS, 16B per lane; LDS dest = wave-uniform base + lane*16
__device__ __forceinline__ void gload16(const unsigned short* g, unsigned short* l) {
    __builtin_amdgcn_global_load_lds(
        (const __attribute__((address_space(1))) unsigned int*)g,
        (__attribute__((address_space(3))) unsigned int*)l, 16, 0, 0);
}

// ---- fp32 router: logits -> softmax -> probs out, argmax -> expert lists ----
__global__ __launch_bounds__(256) void router_kernel(
    const float* __restrict__ x, const float* __restrict__ wr,
    const float* __restrict__ br, float* __restrict__ probs,
    int* __restrict__ cnt, int* __restrict__ list)
{
    __shared__ int lcnt[NEXP];
    __shared__ int lbase[NEXP];
    const int tid = threadIdx.x;
    if (tid < NEXP) lcnt[tid] = 0;
    __syncthreads();

    const int n = blockIdx.x * 256 + tid;
    float acc[NEXP];
    #pragma unroll
    for (int e = 0; e < NEXP; e++) acc[e] = br[e];

    const f32x4* xr = (const f32x4*)(x + (size_t)n * DIM);
    for (int i = 0; i < DIM / 4; i++) {
        f32x4 v = xr[i];
        #pragma unroll
        for (int d = 0; d < 4; d++) {
            const float xv = v[d];
            #pragma unroll
            for (int e = 0; e < NEXP; e++)
                acc[e] += xv * wr[(i * 4 + d) * NEXP + e];  // uniform addr -> scalar load
        }
    }
    // softmax + argmax (first-max wins, matches numpy)
    float mx = acc[0]; int am = 0;
    #pragma unroll
    for (int e = 1; e < NEXP; e++) if (acc[e] > mx) { mx = acc[e]; am = e; }
    float p[NEXP]; float s = 0.f;
    #pragma unroll
    for (int e = 0; e < NEXP; e++) { p[e] = expf(acc[e] - mx); s += p[e]; }
    const float inv = 1.f / s;
    f32x4 p0, p1;
    #pragma unroll
    for (int e = 0; e < 4; e++) { p0[e] = p[e] * inv; p1[e] = p[e + 4] * inv; }
    *(f32x4*)&probs[(size_t)n * NEXP]     = p0;
    *(f32x4*)&probs[(size_t)n * NEXP + 4] = p1;

    const int slot = atomicAdd(&lcnt[am], 1);
    __syncthreads();
    if (tid < NEXP) lbase[tid] = atomicAdd(&cnt[tid], lcnt[tid]);
    __syncthreads();
    list[am * N_TOK + lbase[am] + slot] = n;
}

__global__ void convert_x_kernel(const float* __restrict__ x, unsigned short* __restrict__ xbf) {
    const size_t i = (size_t)blockIdx.x * 256 + threadIdx.x;   // 524288 threads, 8 elems each
    f32x4 a = *(const f32x4*)&x[i * 8];
    f32x4 b = *(const f32x4*)&x[i * 8 + 4];
    u16x8 o;
    #pragma unroll
    for (int j = 0; j < 4; j++) { o[j] = f2bf(a[j]); o[4 + j] = f2bf(b[j]); }
    *(u16x8*)&xbf[i * 8] = o;
}

// merged: z<8 -> W1[e] (512x2048), z>=8 -> W2[e-8] (2048x512); out transposed bf16
__global__ __launch_bounds__(256) void transpose_both_kernel(
    const float* __restrict__ w1, unsigned short* __restrict__ w1t,
    const float* __restrict__ w2, unsigned short* __restrict__ w2t)
{
    __shared__ float t[32][33];
    const int z = blockIdx.z;
    const float* pin; unsigned short* pout; int C, R, r0, c0;
    if (z < NEXP) {
        pin = w1 + (size_t)z * DIM * HID; pout = w1t + (size_t)z * DIM * HID;
        R = DIM; C = HID; r0 = blockIdx.x * 32; c0 = blockIdx.y * 32;
    } else {
        pin = w2 + (size_t)(z - NEXP) * HID * OUTD; pout = w2t + (size_t)(z - NEXP) * HID * OUTD;
        R = HID; C = OUTD; r0 = blockIdx.y * 32; c0 = blockIdx.x * 32;
    }
    const int lr = threadIdx.x >> 3, lc4 = (threadIdx.x & 7) * 4;
    f32x4 v = *(const f32x4*)&pin[(size_t)(r0 + lr) * C + c0 + lc4];
    #pragma unroll
    for (int i = 0; i < 4; i++) t[lr][lc4 + i] = v[i];
    __syncthreads();
    u16x4 o;
    #pragma unroll
    for (int i = 0; i < 4; i++) o[i] = f2bf(t[lc4 + i][lr]);
    *(u16x4*)&pout[(size_t)(c0 + lr) * R + r0 + lc4] = o;
}

// bijective per-XCD chunk swizzle: phys bid -> virtual id in [0,nwg)
__device__ __forceinline__ int xcd_swizzle(int bid, int nwg, bool& valid) {
    const int xcd = bid & 7, cidx = bid >> 3;
    const int q = nwg >> 3, r = nwg & 7;
    const int csz = q + (xcd < r ? 1 : 0);
    valid = (cidx < csz);
    return (xcd < r ? xcd * (q + 1) : r * (q + 1) + (xcd - r) * q) + cidx;
}

// tile -> (expert, row0, base) from cnt[8]; wave-uniform scalar work
__device__ __forceinline__ void tile_map(const int* __restrict__ cnt, int tile,
                                         int& e, int& row0, int& bs, int& m_e, int& ntiles) {
    int c[NEXP]; ntiles = 0;
    #pragma unroll
    for (int i = 0; i < NEXP; i++) { c[i] = cnt[i]; ntiles += (c[i] + 127) >> 7; }
    int t = tile, b = 0, ei = 0;
    #pragma unroll
    for (int i = 0; i < NEXP; i++) {
        const int nt = (c[i] + 127) >> 7;
        const bool here = (t >= 0) && (t < nt);
        if (here) { ei = i; }
        if (t >= 0 && t < nt) { row0 = t * 128; bs = b; m_e = c[i]; }
        t -= nt; b += c[i];
    }
    e = ei;
}

// ---- GEMM1: h[slot, :] = relu(x[tok] @ W1[e] + b1[e]) ; 128x128, BK=64, 2-phase dbuf ----
__global__ __launch_bounds__(256) void gemm1_kernel(
    const unsigned short* __restrict__ xbf, const unsigned short* __restrict__ w1t,
    const float* __restrict__ b1, const int* __restrict__ list,
    const int* __restrict__ cnt, unsigned short* __restrict__ h)
{
    int e = 0, row0 = 0, bs = 0, m_e = 0, ntiles = 0;
    {
        int dummy_tile = 0;
        tile_map(cnt, dummy_tile, e, row0, bs, m_e, ntiles);  // get ntiles first
    }
    const int nwg = ntiles * 16;
    bool valid; const int v = xcd_swizzle(blockIdx.x, nwg, valid);
    if (!valid) return;
    const int tile = v >> 4, ntile = v & 15;
    tile_map(cnt, tile, e, row0, bs, m_e, ntiles);
    const int n0 = ntile * 128;

    __shared__ unsigned short ldsA[2 * 128 * 64] __attribute__((aligned(16)));
    __shared__ unsigned short ldsB[2 * 128 * 64] __attribute__((aligned(16)));
    __shared__ int ldsTok[128];
    const int tid = threadIdx.x;
    if (tid < 128) {
        int r = row0 + tid; if (r >= m_e) r = m_e - 1;
        ldsTok[tid] = list[e * N_TOK + r];
    }
    __syncthreads();

    const int gslot = tid & 7;
    const unsigned short* aSrc[4]; const unsigned short* bSrc[4];
    #pragma unroll
    for (int i = 0; i < 4; i++) {
        const int row = (i * 256 + tid) >> 3;
        const int col = ((gslot ^ (row & 7)) << 3);
        aSrc[i] = xbf + (size_t)ldsTok[row] * DIM + col;
        bSrc[i] = w1t + ((size_t)e * HID + n0 + row) * DIM + col;
    }

    f32x4 acc[4][4] = {};
    const int lane = tid & 63, wid = tid >> 6;
    const int wm = (wid >> 1) * 64, wn = (wid & 1) * 64;
    const int lrow = lane & 15, gk = lane >> 4;

    int offA[4][2], offB[4][2];
    #pragma unroll
    for (int f = 0; f < 4; f++) {
        const int ra = wm + f * 16 + lrow, rb = wn + f * 16 + lrow;
        #pragma unroll
        for (int kk = 0; kk < 2; kk++) {
            offA[f][kk] = ra * 64 + (((kk * 4 + gk) ^ (ra & 7)) << 3);
            offB[f][kk] = rb * 64 + (((kk * 4 + gk) ^ (rb & 7)) << 3);
        }
    }

    auto stage = [&](int buf, int k0) {
        unsigned short* la = ldsA + buf * 8192;
        unsigned short* lb = ldsB + buf * 8192;
        #pragma unroll
        for (int i = 0; i < 4; i++) {
            const int o = ((i << 8) + (tid & 192)) * 8;
            gload16(aSrc[i] + k0, la + o);
            gload16(bSrc[i] + k0, lb + o);
        }
    };
    auto comp = [&](int buf) {
        const unsigned short* la = ldsA + buf * 8192;
        const unsigned short* lb = ldsB + buf * 8192;
        #pragma unroll
        for (int kk = 0; kk < 2; kk++) {
            bf16x8 av[4], bv[4];
            #pragma unroll
            for (int f = 0; f < 4; f++) {
                av[f] = *(const bf16x8*)&la[offA[f][kk]];
                bv[f] = *(const bf16x8*)&lb[offB[f][kk]];
            }
            #pragma unroll
            for (int mf = 0; mf < 4; mf++)
                #pragma unroll
                for (int nf = 0; nf < 4; nf++)
                    acc[mf][nf] = __builtin_amdgcn_mfma_f32_16x16x32_bf16(av[mf], bv[nf], acc[mf][nf], 0, 0, 0);
        }
    };

    // 2-phase pipeline: issue next stage BEFORE compute, one vmcnt(0)+barrier per tile
    stage(0, 0);
    __syncthreads();
    #pragma unroll
    for (int k0 = 0; k0 < DIM - 128; k0 += 128) {
        stage(1, k0 + 64);  comp(0);  __syncthreads();
        stage(0, k0 + 128); comp(1);  __syncthreads();
    }
    stage(1, DIM - 64); comp(0); __syncthreads();
    comp(1);

    const int hbase = bs + row0;
    float bias[4];
    #pragma unroll
    for (int nf = 0; nf < 4; nf++) bias[nf] = b1[e * HID + n0 + wn + nf * 16 + lrow];
    #pragma unroll
    for (int mf = 0; mf < 4; mf++) {
        #pragma unroll
        for (int j = 0; j < 4; j++) {
            const int m = wm + mf * 16 + (lane >> 4) * 4 + j;
            if (row0 + m < m_e) {
                const size_t ro = (size_t)(hbase + m) * HID + n0 + wn;
                #pragma unroll
                for (int nf = 0; nf < 4; nf++) {
                    float vv = acc[mf][nf][j] + bias[nf];
                    h[ro + nf * 16 + lrow] = f2bf(vv > 0.f ? vv : 0.f);
                }
            }
        }
    }
}

// ---- GEMM2: out[tok, :] = h[slot] @ W2[e] + b2[e] ; 128x64, BK=64, K=2048, 2-phase dbuf ----
__global__ __launch_bounds__(256) void gemm2_kernel(
    const unsigned short* __restrict__ h, const unsigned short* __restrict__ w2t,
    const float* __restrict__ b2, const int* __restrict__ list,
    const int* __restrict__ cnt, float* __restrict__ out, float* __restrict__ counts)
{
    const int tid = threadIdx.x;
    if (blockIdx.x == 0 && tid < NEXP) counts[tid] = (float)cnt[tid];

    int e = 0, row0 = 0, bs = 0, m_e = 0, ntiles = 0;
    {
        int dummy_tile = 0;
        tile_map(cnt, dummy_tile, e, row0, bs, m_e, ntiles);
    }
    const int nwg = ntiles * 8;
    bool valid; const int v = xcd_swizzle(blockIdx.x, nwg, valid);
    if (!valid) return;
    const int tile = v >> 3, ntile = v & 7;
    tile_map(cnt, tile, e, row0, bs, m_e, ntiles);
    const int n0 = ntile * 64;

    __shared__ unsigned short ldsA[2 * 128 * 64] __attribute__((aligned(16)));
    __shared__ unsigned short ldsB[2 * 64 * 64]  __attribute__((aligned(16)));
    __shared__ int ldsTok[128];
    if (tid < 128) {
        int r = row0 + tid; if (r >= m_e) r = m_e - 1;
        ldsTok[tid] = list[e * N_TOK + r];
    }

    const int gslot = tid & 7;
    const unsigned short* aSrc[4]; const unsigned short* bSrc[2];
    #pragma unroll
    for (int i = 0; i < 4; i++) {
        const int row = (i * 256 + tid) >> 3;
        int slot = row0 + row; if (slot >= m_e) slot = m_e - 1;
        aSrc[i] = h + (size_t)(bs + slot) * HID + ((gslot ^ (row & 7)) << 3);
    }
    #pragma unroll
    for (int i = 0; i < 2; i++) {
        const int row = (i * 256 + tid) >> 3;   // 0..63
        bSrc[i] = w2t + ((size_t)e * OUTD + n0 + row) * HID + ((gslot ^ (row & 7)) << 3);
    }

    f32x4 acc[4][2] = {};
    const int lane = tid & 63, wid = tid >> 6;
    const int wm = (wid >> 1) * 64, wn = (wid & 1) * 32;
    const int lrow = lane & 15, gk = lane >> 4;

    int offA[4][2], offB[2][2];
    #pragma unroll
    for (int f = 0; f < 4; f++) {
        const int ra = wm + f * 16 + lrow;
        #pragma unroll
        for (int kk = 0; kk < 2; kk++)
            offA[f][kk] = ra * 64 + (((kk * 4 + gk) ^ (ra & 7)) << 3);
    }
    #pragma unroll
    for (int f = 0; f < 2; f++) {
        const int rb = wn + f * 16 + lrow;
        #pragma unroll
        for (int kk = 0; kk < 2; kk++)
            offB[f][kk] = rb * 64 + (((kk * 4 + gk) ^ (rb & 7)) << 3);
    }

    auto stage = [&](int buf, int k0) {
        unsigned short* la = ldsA + buf * 8192;
        unsigned short* lb = ldsB + buf * 4096;
        #pragma unroll
        for (int i = 0; i < 4; i++) {
            const int o = ((i << 8) + (tid & 192)) * 8;
            gload16(aSrc[i] + k0, la + o);
        }
        #pragma unroll
        for (int i = 0; i < 2; i++) {
            const int o = ((i << 8) + (tid & 192)) * 8;
            gload16(bSrc[i] + k0, lb + o);
        }
    };
    auto comp = [&](int buf) {
        const unsigned short* la = ldsA + buf * 8192;
        const unsigned short* lb = ldsB + buf * 4096;
        #pragma unroll
        for (int kk = 0; kk < 2; kk++) {
            bf16x8 av[4], bv[2];
            #pragma unroll
            for (int f = 0; f < 4; f++)
                av[f] = *(const bf16x8*)&la[offA[f][kk]];
            #pragma unroll
            for (int f = 0; f < 2; f++)
                bv[f] = *(const bf16x8*)&lb[offB[f][kk]];
            #pragma unroll
            for (int mf = 0; mf < 4; mf++)
                #pragma unroll
                for (int nf = 0; nf < 2; nf++)
                    acc[mf][nf] = __builtin_amdgcn_mfma_f32_16x16x32_bf16(av[mf], bv[nf], acc[mf][nf], 0, 0, 0);
        }
    };

    __syncthreads();           // ldsTok visible
    stage(0, 0);
    __syncthreads();
    for (int k0 = 0; k0 < HID - 128; k0 += 128) {
        stage(1, k0 + 64);  comp(0);  __syncthreads();
        stage(0, k0 + 128); comp(1);  __syncthreads();
    }
    stage(1, HID - 64); comp(0); __syncthreads();
    comp(1);

    float bias[2];
    #pragma unroll
    for (int nf = 0; nf < 2; nf++) bias[nf] = b2[e * OUTD + n0 + wn + nf * 16 + lrow];
    #pragma unroll
    for (int mf = 0; mf < 4; mf++) {
        #pragma unroll
        for (int j = 0; j < 4; j++) {
            const int m = wm + mf * 16 + (lane >> 4) * 4 + j;
            if (row0 + m < m_e) {
                const size_t ro = (size_t)ldsTok[m] * OUTD + n0 + wn;
                #pragma unroll
                for (int nf = 0; nf < 2; nf++)
                    out[ro + nf * 16 + lrow] = acc[mf][nf][j] + bias[nf];
            }
        }
    }
}

extern "C" void kernel_launch(void* const* d_in, const int* in_sizes, int n_in,
                              void* d_out, int out_size, void* d_ws, size_t ws_size,
                              hipStream_t stream) {
    (void)in_sizes; (void)n_in; (void)out_size; (void)ws_size;
    const float* x  = (const float*)d_in[0];
    const float* wr = (const float*)d_in[1];
    const float* br = (const float*)d_in[2];
    const float* w1 = (const float*)d_in[3];
    const float* b1 = (const float*)d_in[4];
    const float* w2 = (const float*)d_in[5];
    const float* b2 = (const float*)d_in[6];

    float* out    = (float*)d_out;
    float* probs  = out + (size_t)N_TOK * OUTD;
    float* counts = probs + (size_t)N_TOK * NEXP;

    char* ws = (char*)d_ws;
    int* cnt     = (int*)(ws + WS_CNT);
    int* list    = (int*)(ws + WS_LIST);
    unsigned short* xbf = (unsigned short*)(ws + WS_XBF);
    unsigned short* w1t = (unsigned short*)(ws + WS_W1T);
    unsigned short* w2t = (unsigned short*)(ws + WS_W2T);
    unsigned short* hbf = (unsigned short*)(ws + WS_H);

    hipMemsetAsync(cnt, 0, NEXP * sizeof(int), stream);
    router_kernel<<<32, 256, 0, stream>>>(x, wr, br, probs, cnt, list);
    convert_x_kernel<<<2048, 256, 0, stream>>>(x, xbf);
    transpose_both_kernel<<<dim3(16, 64, 16), 256, 0, stream>>>(w1, w1t, w2, w2t);
    gemm1_kernel<<<1280, 256, 0, stream>>>(xbf, w1t, b1, list, cnt, hbf);
    gemm2_kernel<<<640, 256, 0, stream>>>(hbf, w2t, b2, list, cnt, out, counts);
}